// Round 2
// baseline (681.219 us; speedup 1.0000x reference)
//
#include <hip/hip_runtime.h>

// Fused 2-layer LSTM + FC head: B=4096, T=128, D=32, H1=64, H2=32.
// grid=256 (1 block/CU), block=512 (8 waves). 16 batches/block.
// L1 weights register-resident (96 VGPR/thread), k-sliced 8-way with
// ds_swizzle reduce-scatter. h/x tiles transposed [k][batch] in LDS.

constexpr int Tt      = 128;
constexpr int NB      = 16;
constexpr int THREADS = 512;

struct __align__(16) Smem {
  float w2t[96][132];      // L2 weights, resident: [k][unit*4+gate], stride 132 (50688 B)
  float scr[48][256];      // L1 weight staging scratch, dead after init   (49152 B)
  float h1t[2][64][20];    // h1 state, transposed [unit][batch]           (10240 B)
  float h2t[2][32][20];    // h2 state                                     ( 5120 B)
  float xs [2][32][20];    // x_t tile, transposed [d][batch]              ( 5120 B)
};                         // total 120320 B

static_assert(sizeof(Smem) <= 160 * 1024, "LDS overflow");

__device__ __forceinline__ float frcp(float x)   { return __builtin_amdgcn_rcpf(x); }
__device__ __forceinline__ float fsig(float x)   { return frcp(1.0f + __expf(-x)); }
__device__ __forceinline__ float ftanh_(float x) { return 1.0f - 2.0f * frcp(1.0f + __expf(2.0f * x)); }

template<int P>
__device__ __forceinline__ float swz(float v) {
  return __int_as_float(__builtin_amdgcn_ds_swizzle(__float_as_int(v), P));
}

__global__ __launch_bounds__(THREADS, 2)
void lstm_fused(const float* __restrict__ x,
                const float* __restrict__ Wih1, const float* __restrict__ Whh1,
                const float* __restrict__ bih1, const float* __restrict__ bhh1,
                const float* __restrict__ Wih2, const float* __restrict__ Whh2,
                const float* __restrict__ bih2, const float* __restrict__ bhh2,
                const float* __restrict__ fc1w, const float* __restrict__ fc1b,
                const float* __restrict__ fc2w, const float* __restrict__ fc2b,
                float* __restrict__ out)
{
  __shared__ Smem s;
  const int tid = threadIdx.x;
  const int wv  = tid >> 6;
  const int l   = tid & 63;
  const int b0  = blockIdx.x * NB;

  // lane roles: ks = k-slice (reduction group, lane bits 0..2),
  // bh = batch half (bit 3), pq = unit selector (bits 4..5)
  const int ks  = l & 7;
  const int bh  = (l >> 3) & 1;
  const int pq  = l >> 4;
  const int up  = wv * 4 + pq;     // L1 unit-pair 0..31 -> units {2up,2up+1}
  const int u2  = wv * 4 + pq;     // L2 unit 0..31
  const int bh8 = bh * 8;
  const int myb = bh8 + ks;        // batch this lane finalizes

  // ---------------- one-time staging ----------------
  // L2 weights -> w2t[k][u*4+g]  (k<64: Wih2 over h1; k>=64: Whh2 over h2)
  for (int e = tid; e < 128 * 64; e += THREADS) {            // Wih2 (128x64)
    int r = e >> 6, k = e & 63;
    s.w2t[k][(r & 31) * 4 + (r >> 5)] = Wih2[e];
  }
  for (int e = tid; e < 128 * 32; e += THREADS) {            // Whh2 (128x32)
    int r = e >> 5, k = e & 31;
    s.w2t[64 + k][(r & 31) * 4 + (r >> 5)] = Whh2[e];
  }
  // L1 chunk A: k in [0,48)  (Wih1 cols 0..31, Whh1 cols 0..15)
  for (int e = tid; e < 256 * 32; e += THREADS) {            // Wih1 (256x32)
    int r = e >> 5, k = e & 31;
    s.scr[k][(r & 63) * 4 + (r >> 6)] = Wih1[e];
  }
  for (int e = tid; e < 256 * 16; e += THREADS) {            // Whh1 cols 0..15
    int r = e >> 4, kc = e & 15;
    s.scr[32 + kc][(r & 63) * 4 + (r >> 6)] = Whh1[r * 64 + kc];
  }
  __syncthreads();

  // register-load L1 weights, j = 0..5  (k = ks + 8j in [0,48))
  float w1[12][8];
#pragma unroll
  for (int j = 0; j < 6; ++j) {
    int k = ks + 8 * j;
    float4 a4 = *(const float4*)&s.scr[k][up * 8];
    float4 b4 = *(const float4*)&s.scr[k][up * 8 + 4];
    w1[j][0] = a4.x; w1[j][1] = a4.y; w1[j][2] = a4.z; w1[j][3] = a4.w;
    w1[j][4] = b4.x; w1[j][5] = b4.y; w1[j][6] = b4.z; w1[j][7] = b4.w;
  }
  __syncthreads();

  // L1 chunk B: k in [48,96)  (Whh1 cols 16..63) -> scr rows 0..47
  for (int e = tid; e < 256 * 64; e += THREADS) {
    int r = e >> 6, k = e & 63;
    if (k >= 16) s.scr[k - 16][(r & 63) * 4 + (r >> 6)] = Whh1[e];
  }
  // zero initial state (buffer 0 only; buffer 1 written before first read)
  for (int e = tid; e < 64 * 20; e += THREADS) (&s.h1t[0][0][0])[e] = 0.0f;
  for (int e = tid; e < 32 * 20; e += THREADS) (&s.h2t[0][0][0])[e] = 0.0f;
  __syncthreads();

#pragma unroll
  for (int j = 6; j < 12; ++j) {
    int k = ks + 8 * j;          // in [48,96)
    float4 a4 = *(const float4*)&s.scr[k - 48][up * 8];
    float4 b4 = *(const float4*)&s.scr[k - 48][up * 8 + 4];
    w1[j][0] = a4.x; w1[j][1] = a4.y; w1[j][2] = a4.z; w1[j][3] = a4.w;
    w1[j][4] = b4.x; w1[j][5] = b4.y; w1[j][6] = b4.z; w1[j][7] = b4.w;
  }

  // biases (fused bih+bhh), per finalized (unit, batch)
  float bias1[8], bias2[4];
#pragma unroll
  for (int uu = 0; uu < 2; ++uu)
#pragma unroll
    for (int g = 0; g < 4; ++g) {
      int u = 2 * up + uu;
      bias1[uu * 4 + g] = bih1[g * 64 + u] + bhh1[g * 64 + u];
    }
#pragma unroll
  for (int g = 0; g < 4; ++g) bias2[g] = bih2[g * 32 + u2] + bhh2[g * 32 + u2];

  // x staging: thread owns (xb, xd); coalesced global read, transposed LDS write
  const int    xb   = tid >> 5;          // 0..15 batch
  const int    xd   = tid & 31;          // 0..31 feature
  const float* xptr = x + (size_t)(b0 + xb) * (Tt * 32) + xd;
  s.xs[0][xd][xb] = xptr[0];

  float c1[2] = {0.0f, 0.0f};
  float c2    = 0.0f;

  const bool k0b = (ks & 1) != 0;
  const bool k1b = (ks & 2) != 0;
  const bool k2b = (ks & 4) != 0;

  __syncthreads();

#pragma unroll 1
  for (int t = 0; t < Tt; ++t) {
    const int c = t & 1, n = c ^ 1;

    // prefetch next x element (consumed after barrier A)
    float xpre = 0.0f;
    if (t + 1 < Tt) xpre = xptr[(size_t)(t + 1) * 32];

    // ============ Layer 1: partial gates, k = ks + 8j ============
    float a[8][8];
#pragma unroll
    for (int g = 0; g < 8; ++g)
#pragma unroll
      for (int b = 0; b < 8; ++b) a[g][b] = 0.0f;

#pragma unroll
    for (int j = 0; j < 12; ++j) {
      const float* hrow = (j < 4) ? &s.xs[c][ks + 8 * j][0]
                                  : &s.h1t[c][ks + 8 * j - 32][0];
      float4 h0 = *(const float4*)(hrow + bh8);
      float4 h1 = *(const float4*)(hrow + bh8 + 4);
      float hv[8] = {h0.x, h0.y, h0.z, h0.w, h1.x, h1.y, h1.z, h1.w};
#pragma unroll
      for (int g = 0; g < 8; ++g)
#pragma unroll
        for (int b = 0; b < 8; ++b)
          a[g][b] = fmaf(w1[j][g], hv[b], a[g][b]);
    }

    // reduce-scatter over 8 k-slices: lane ends with batch myb
    float tot[8];
#pragma unroll
    for (int g = 0; g < 8; ++g) {
      float r1[4], r2[2];
#pragma unroll
      for (int i = 0; i < 4; ++i) {
        float snd  = k0b ? a[g][2 * i]     : a[g][2 * i + 1];
        float kept = k0b ? a[g][2 * i + 1] : a[g][2 * i];
        r1[i] = kept + swz<0x041F>(snd);
      }
#pragma unroll
      for (int i = 0; i < 2; ++i) {
        float snd  = k1b ? r1[2 * i]     : r1[2 * i + 1];
        float kept = k1b ? r1[2 * i + 1] : r1[2 * i];
        r2[i] = kept + swz<0x081F>(snd);
      }
      float snd  = k2b ? r2[0] : r2[1];
      float kept = k2b ? r2[1] : r2[0];
      tot[g] = kept + swz<0x101F>(snd);
    }

    // finalize L1: this lane owns units {2up,2up+1}, batch myb
#pragma unroll
    for (int uu = 0; uu < 2; ++uu) {
      float iv = fsig  (tot[4 * uu + 0] + bias1[4 * uu + 0]);
      float fv = fsig  (tot[4 * uu + 1] + bias1[4 * uu + 1]);
      float gv = ftanh_(tot[4 * uu + 2] + bias1[4 * uu + 2]);
      float ov = fsig  (tot[4 * uu + 3] + bias1[4 * uu + 3]);
      c1[uu] = fv * c1[uu] + iv * gv;
      s.h1t[n][2 * up + uu][myb] = ov * ftanh_(c1[uu]);
    }
    __syncthreads();   // A: h1(t) complete; xs[c] fully consumed

    if (t + 1 < Tt) s.xs[n][xd][xb] = xpre;

    // ============ Layer 2 ============
    float a2[4][8];
#pragma unroll
    for (int g = 0; g < 4; ++g)
#pragma unroll
      for (int b = 0; b < 8; ++b) a2[g][b] = 0.0f;

#pragma unroll
    for (int j = 0; j < 12; ++j) {
      const int k = ks + 8 * j;
      const float* hrow = (j < 8) ? &s.h1t[n][k][0] : &s.h2t[c][k - 64][0];
      float4 wv4 = *(const float4*)&s.w2t[k][u2 * 4];
      float4 h0  = *(const float4*)(hrow + bh8);
      float4 h1  = *(const float4*)(hrow + bh8 + 4);
      float wvv[4] = {wv4.x, wv4.y, wv4.z, wv4.w};
      float hv[8]  = {h0.x, h0.y, h0.z, h0.w, h1.x, h1.y, h1.z, h1.w};
#pragma unroll
      for (int g = 0; g < 4; ++g)
#pragma unroll
        for (int b = 0; b < 8; ++b)
          a2[g][b] = fmaf(wvv[g], hv[b], a2[g][b]);
    }

    float tot2[4];
#pragma unroll
    for (int g = 0; g < 4; ++g) {
      float r1[4], r2[2];
#pragma unroll
      for (int i = 0; i < 4; ++i) {
        float snd  = k0b ? a2[g][2 * i]     : a2[g][2 * i + 1];
        float kept = k0b ? a2[g][2 * i + 1] : a2[g][2 * i];
        r1[i] = kept + swz<0x041F>(snd);
      }
#pragma unroll
      for (int i = 0; i < 2; ++i) {
        float snd  = k1b ? r1[2 * i]     : r1[2 * i + 1];
        float kept = k1b ? r1[2 * i + 1] : r1[2 * i];
        r2[i] = kept + swz<0x081F>(snd);
      }
      float snd  = k2b ? r2[0] : r2[1];
      float kept = k2b ? r2[1] : r2[0];
      tot2[g] = kept + swz<0x101F>(snd);
    }

    {
      float iv = fsig  (tot2[0] + bias2[0]);
      float fv = fsig  (tot2[1] + bias2[1]);
      float gv = ftanh_(tot2[2] + bias2[2]);
      float ov = fsig  (tot2[3] + bias2[3]);
      c2 = fv * c2 + iv * gv;
      s.h2t[n][u2][myb] = ov * ftanh_(c2);
    }
    __syncthreads();   // B: h2(t), xs[next] visible for next step
  }

  // ---------------- FC head ----------------
  // final h2 is in buffer 0 (t=127 wrote n = 0); h2t[1] is dead -> scratch
  float* fc1out = &s.h2t[1][0][0];   // [16 batches][16 units]
  if (tid < 256) {
    const int fb = tid >> 4, fu = tid & 15;
    float sacc = fc1b[fu];
#pragma unroll
    for (int k = 0; k < 32; ++k)
      sacc = fmaf(fc1w[fu * 32 + k], s.h2t[0][k][fb], sacc);
    fc1out[fb * 16 + fu] = fmaxf(sacc, 0.0f);
  }
  __syncthreads();
  if (tid < 16) {
    float o = fc2b[0];
#pragma unroll
    for (int u = 0; u < 16; ++u) o = fmaf(fc2w[u], fc1out[tid * 16 + u], o);
    out[b0 + tid] = o;
  }
}

extern "C" void kernel_launch(void* const* d_in, const int* in_sizes, int n_in,
                              void* d_out, int out_size, void* d_ws, size_t ws_size,
                              hipStream_t stream) {
  const float* x    = (const float*)d_in[0];
  const float* Wih1 = (const float*)d_in[1];
  const float* Whh1 = (const float*)d_in[2];
  const float* bih1 = (const float*)d_in[3];
  const float* bhh1 = (const float*)d_in[4];
  const float* Wih2 = (const float*)d_in[5];
  const float* Whh2 = (const float*)d_in[6];
  const float* bih2 = (const float*)d_in[7];
  const float* bhh2 = (const float*)d_in[8];
  const float* fc1w = (const float*)d_in[9];
  const float* fc1b = (const float*)d_in[10];
  const float* fc2w = (const float*)d_in[11];
  const float* fc2b = (const float*)d_in[12];
  float* out = (float*)d_out;

  hipLaunchKernelGGL(lstm_fused, dim3(256), dim3(THREADS), 0, stream,
                     x, Wih1, Whh1, bih1, bhh1,
                     Wih2, Whh2, bih2, bhh2,
                     fc1w, fc1b, fc2w, fc2b, out);
}

// Round 3
// 675.665 us; speedup vs baseline: 1.0082x; 1.0082x over previous
//
#include <hip/hip_runtime.h>

// Fused 2-layer LSTM + FC head: B=4096, T=128, D=32, H1=64, H2=32.
// 256 threads/block, NB=8 batches/block, grid=512 (2 blocks/CU).
// ALL weights register-resident: L1 4-way k-sliced (96 VGPR), L2 8-way (48 VGPR).
// LDS holds only h/x state (transposed [unit][batch]) + 32KB one-time staging.

constexpr int Tt      = 128;
constexpr int NB      = 8;
constexpr int THREADS = 256;

struct __align__(16) Smem {
  float scr[8192];          // staging scratch (32 KB), dead after init
  float h1t[2][64][12];     // [buf][unit][batch(8)+pad]   (6144 B)
  float h2t[2][32][12];     //                              (3072 B)
  float xs [2][32][12];     // [buf][d][batch]              (3072 B)
};                          // total 45056 B -> 2 blocks/CU

static_assert(sizeof(Smem) <= 80 * 1024, "need 2 blocks/CU");

__device__ __forceinline__ float frcp(float x)   { return __builtin_amdgcn_rcpf(x); }
__device__ __forceinline__ float fsig(float x)   { return frcp(1.0f + __expf(-x)); }
__device__ __forceinline__ float ftanh_(float x) { return 1.0f - 2.0f * frcp(1.0f + __expf(2.0f * x)); }

template<int P>
__device__ __forceinline__ float swz(float v) {
  return __int_as_float(__builtin_amdgcn_ds_swizzle(__float_as_int(v), P));
}

__global__ __launch_bounds__(THREADS, 2)
void lstm_fused(const float* __restrict__ x,
                const float* __restrict__ Wih1, const float* __restrict__ Whh1,
                const float* __restrict__ bih1, const float* __restrict__ bhh1,
                const float* __restrict__ Wih2, const float* __restrict__ Whh2,
                const float* __restrict__ bih2, const float* __restrict__ bhh2,
                const float* __restrict__ fc1w, const float* __restrict__ fc1b,
                const float* __restrict__ fc2w, const float* __restrict__ fc2b,
                float* __restrict__ out)
{
  __shared__ Smem s;
  const int tid = threadIdx.x;
  const int b0  = blockIdx.x * NB;

  // L1 role: 4-way k-slice, one unit per lane
  const int ks1 = tid & 3;          // k-slice 0..3
  const int u1  = tid >> 2;         // unit 0..63
  // L2 role: 8-way k-slice
  const int ks2 = tid & 7;          // k-slice 0..7 (also final batch)
  const int u2  = tid >> 3;         // unit 0..31

  float w1[24][4];                  // L1 weights: k = ks1+4j, gate g
  float w2[12][4];                  // L2 weights: k = ks2+8j, gate g

  auto stage = [&](const float* g, int n) {
    for (int e = tid * 4; e < n; e += THREADS * 4)
      *(float4*)&s.scr[e] = *(const float4*)&g[e];
  };

  // ---- phase 1: Wih1 [256][32] ----
  stage(Wih1, 8192);
  __syncthreads();
#pragma unroll
  for (int j = 0; j < 8; ++j)
#pragma unroll
    for (int g = 0; g < 4; ++g)
      w1[j][g] = s.scr[(g * 64 + u1) * 32 + ks1 + 4 * j];
  __syncthreads();

  // ---- phase 2: Whh1 rows 0..127 (g=0,1) [.][64] ----
  stage(Whh1, 8192);
  __syncthreads();
#pragma unroll
  for (int j = 8; j < 24; ++j)
#pragma unroll
    for (int g = 0; g < 2; ++g)
      w1[j][g] = s.scr[(g * 64 + u1) * 64 + ks1 + 4 * (j - 8)];
  __syncthreads();

  // ---- phase 3: Whh1 rows 128..255 (g=2,3) ----
  stage(Whh1 + 8192, 8192);
  __syncthreads();
#pragma unroll
  for (int j = 8; j < 24; ++j)
#pragma unroll
    for (int g = 2; g < 4; ++g)
      w1[j][g] = s.scr[((g - 2) * 64 + u1) * 64 + ks1 + 4 * (j - 8)];
  __syncthreads();

  // ---- phase 4: Wih2 [128][64] ----
  stage(Wih2, 8192);
  __syncthreads();
#pragma unroll
  for (int j = 0; j < 8; ++j)
#pragma unroll
    for (int g = 0; g < 4; ++g)
      w2[j][g] = s.scr[(g * 32 + u2) * 64 + ks2 + 8 * j];
  __syncthreads();

  // ---- phase 5: Whh2 [128][32] ----
  stage(Whh2, 4096);
  __syncthreads();
#pragma unroll
  for (int j = 8; j < 12; ++j)
#pragma unroll
    for (int g = 0; g < 4; ++g)
      w2[j][g] = s.scr[(g * 32 + u2) * 32 + ks2 + 8 * (j - 8)];

  // biases (fused)
  float bias1[4], bias2[4];
#pragma unroll
  for (int g = 0; g < 4; ++g) {
    bias1[g] = bih1[g * 64 + u1] + bhh1[g * 64 + u1];
    bias2[g] = bih2[g * 32 + u2] + bhh2[g * 32 + u2];
  }

  // zero initial state (buffer 0)
  for (int e = tid; e < 64 * 12; e += THREADS) (&s.h1t[0][0][0])[e] = 0.0f;
  for (int e = tid; e < 32 * 12; e += THREADS) (&s.h2t[0][0][0])[e] = 0.0f;

  // x staging: thread owns (xb, xd); coalesced global, transposed LDS
  const int    xb   = tid >> 5;     // 0..7
  const int    xd   = tid & 31;     // 0..31
  const float* xptr = x + (size_t)(b0 + xb) * (Tt * 32) + xd;
  s.xs[0][xd][xb] = xptr[0];

  float c1[2] = {0.0f, 0.0f};       // lane's batches: ks1, ks1+4
  float c2    = 0.0f;               // lane's batch: ks2

  const bool sA = (ks1 & 1) != 0;
  const bool sB = (ks1 & 2) != 0;
  const bool t0 = (ks2 & 1) != 0;
  const bool t1 = (ks2 & 2) != 0;
  const bool t2 = (ks2 & 4) != 0;

  __syncthreads();

#pragma unroll 1
  for (int t = 0; t < Tt; ++t) {
    const int c = t & 1, n = c ^ 1;

    float xpre = 0.0f;
    if (t + 1 < Tt) xpre = xptr[(size_t)(t + 1) * 32];

    // ============ Layer 1: partials over k = ks1 + 4j ============
    float a[4][8];
#pragma unroll
    for (int g = 0; g < 4; ++g)
#pragma unroll
      for (int b = 0; b < 8; ++b) a[g][b] = 0.0f;

#pragma unroll
    for (int j = 0; j < 24; ++j) {
      const float* row = (j < 8) ? &s.xs[c][ks1 + 4 * j][0]
                                 : &s.h1t[c][ks1 + 4 * j - 32][0];
      float4 h0 = *(const float4*)&row[0];
      float4 h1 = *(const float4*)&row[4];
      float hv[8] = {h0.x, h0.y, h0.z, h0.w, h1.x, h1.y, h1.z, h1.w};
#pragma unroll
      for (int g = 0; g < 4; ++g)
#pragma unroll
        for (int b = 0; b < 8; ++b)
          a[g][b] = fmaf(w1[j][g], hv[b], a[g][b]);
    }

    // 2-round reduce-scatter across 4 slices -> lane owns batches {ks1, ks1+4}
    float tot[4][2];
#pragma unroll
    for (int g = 0; g < 4; ++g) {
      float r1[4];
#pragma unroll
      for (int i = 0; i < 4; ++i) {
        float snd  = sA ? a[g][2 * i]     : a[g][2 * i + 1];
        float kept = sA ? a[g][2 * i + 1] : a[g][2 * i];
        r1[i] = kept + swz<0x041F>(snd);
      }
#pragma unroll
      for (int i = 0; i < 2; ++i) {
        float snd  = sB ? r1[2 * i]     : r1[2 * i + 1];
        float kept = sB ? r1[2 * i + 1] : r1[2 * i];
        tot[g][i] = kept + swz<0x081F>(snd);
      }
    }

#pragma unroll
    for (int bb = 0; bb < 2; ++bb) {
      float iv = fsig  (tot[0][bb] + bias1[0]);
      float fv = fsig  (tot[1][bb] + bias1[1]);
      float gv = ftanh_(tot[2][bb] + bias1[2]);
      float ov = fsig  (tot[3][bb] + bias1[3]);
      c1[bb] = fv * c1[bb] + iv * gv;
      s.h1t[n][u1][ks1 + 4 * bb] = ov * ftanh_(c1[bb]);
    }
    __syncthreads();   // A: h1(t) complete; xs[c] consumed

    if (t + 1 < Tt) s.xs[n][xd][xb] = xpre;

    // ============ Layer 2: partials over k = ks2 + 8j ============
    float a2[4][8];
#pragma unroll
    for (int g = 0; g < 4; ++g)
#pragma unroll
      for (int b = 0; b < 8; ++b) a2[g][b] = 0.0f;

#pragma unroll
    for (int j = 0; j < 12; ++j) {
      const int k = ks2 + 8 * j;
      const float* row = (j < 8) ? &s.h1t[n][k][0] : &s.h2t[c][k - 64][0];
      float4 h0 = *(const float4*)&row[0];
      float4 h1 = *(const float4*)&row[4];
      float hv[8] = {h0.x, h0.y, h0.z, h0.w, h1.x, h1.y, h1.z, h1.w};
#pragma unroll
      for (int g = 0; g < 4; ++g)
#pragma unroll
        for (int b = 0; b < 8; ++b)
          a2[g][b] = fmaf(w2[j][g], hv[b], a2[g][b]);
    }

    // 3-round reduce-scatter across 8 slices -> lane owns batch ks2
    float tot2[4];
#pragma unroll
    for (int g = 0; g < 4; ++g) {
      float r1[4];
#pragma unroll
      for (int i = 0; i < 4; ++i) {
        float snd  = t0 ? a2[g][2 * i]     : a2[g][2 * i + 1];
        float kept = t0 ? a2[g][2 * i + 1] : a2[g][2 * i];
        r1[i] = kept + swz<0x041F>(snd);
      }
      float r2[2];
#pragma unroll
      for (int i = 0; i < 2; ++i) {
        float snd  = t1 ? r1[2 * i]     : r1[2 * i + 1];
        float kept = t1 ? r1[2 * i + 1] : r1[2 * i];
        r2[i] = kept + swz<0x081F>(snd);
      }
      float snd  = t2 ? r2[0] : r2[1];
      float kept = t2 ? r2[1] : r2[0];
      tot2[g] = kept + swz<0x101F>(snd);
    }

    {
      float iv = fsig  (tot2[0] + bias2[0]);
      float fv = fsig  (tot2[1] + bias2[1]);
      float gv = ftanh_(tot2[2] + bias2[2]);
      float ov = fsig  (tot2[3] + bias2[3]);
      c2 = fv * c2 + iv * gv;
      s.h2t[n][u2][ks2] = ov * ftanh_(c2);
    }
    __syncthreads();   // B: h2(t), xs[next] visible
  }

  // ---------------- FC head ----------------
  // final h2 in buffer 0 (t=127 wrote n=0); scr is dead -> scratch
  float* fc1out = s.scr;            // [8 batches][16 units]
  if (tid < 128) {
    const int fb = tid >> 4, fu = tid & 15;
    float sacc = fc1b[fu];
#pragma unroll
    for (int k = 0; k < 32; ++k)
      sacc = fmaf(fc1w[fu * 32 + k], s.h2t[0][k][fb], sacc);
    fc1out[fb * 16 + fu] = fmaxf(sacc, 0.0f);
  }
  __syncthreads();
  if (tid < NB) {
    float o = fc2b[0];
#pragma unroll
    for (int u = 0; u < 16; ++u) o = fmaf(fc2w[u], fc1out[tid * 16 + u], o);
    out[b0 + tid] = o;
  }
}

extern "C" void kernel_launch(void* const* d_in, const int* in_sizes, int n_in,
                              void* d_out, int out_size, void* d_ws, size_t ws_size,
                              hipStream_t stream) {
  const float* x    = (const float*)d_in[0];
  const float* Wih1 = (const float*)d_in[1];
  const float* Whh1 = (const float*)d_in[2];
  const float* bih1 = (const float*)d_in[3];
  const float* bhh1 = (const float*)d_in[4];
  const float* Wih2 = (const float*)d_in[5];
  const float* Whh2 = (const float*)d_in[6];
  const float* bih2 = (const float*)d_in[7];
  const float* bhh2 = (const float*)d_in[8];
  const float* fc1w = (const float*)d_in[9];
  const float* fc1b = (const float*)d_in[10];
  const float* fc2w = (const float*)d_in[11];
  const float* fc2b = (const float*)d_in[12];
  float* out = (float*)d_out;

  hipLaunchKernelGGL(lstm_fused, dim3(4096 / NB), dim3(THREADS), 0, stream,
                     x, Wih1, Whh1, bih1, bhh1,
                     Wih2, Whh2, bih2, bhh2,
                     fc1w, fc1b, fc2w, fc2b, out);
}

// Round 4
// 638.040 us; speedup vs baseline: 1.0677x; 1.0590x over previous
//
#include <hip/hip_runtime.h>

// Fused 2-layer LSTM + FC head: B=4096, T=128, D=32, H1=64, H2=32.
// 256 threads/block, NB=8 batches/block, grid=512 (2 blocks/CU).
// Gate matmuls via v_dot2_f32_f16 (2 MAC/inst, f32 accumulate): weights
// register-resident as half2 k-pairs; h/x state in LDS as half2[kpair][batch].
// L1 4-way k-sliced, L2 8-way, ds_swizzle reduce-scatter (unchanged).

typedef _Float16 f16;
typedef f16 h2f __attribute__((ext_vector_type(2)));
typedef f16 h8f __attribute__((ext_vector_type(8)));

constexpr int Tt      = 128;
constexpr int NB      = 8;
constexpr int THREADS = 256;

struct __align__(16) Smem {
  float scr[8192];           // 32KB staging scratch, dead after init (reused by FC)
  h2f h1p[2][32][8];         // [buf][unit-pair][batch]  units {2r,2r+1}   2048 B
  h2f h2p[2][16][8];         //                                            1024 B
  h2f xsp[2][16][8];         // [buf][feat-pair][batch]  feats {2r,2r+1}   1024 B
};                           // total 36864 B

static_assert(sizeof(Smem) <= 80 * 1024, "need 2 blocks/CU");

__device__ __forceinline__ float frcp(float x)   { return __builtin_amdgcn_rcpf(x); }
__device__ __forceinline__ float fsig(float x)   { return frcp(1.0f + __expf(-x)); }
__device__ __forceinline__ float ftanh_(float x) { return 1.0f - 2.0f * frcp(1.0f + __expf(2.0f * x)); }

template<int P>
__device__ __forceinline__ float swz(float v) {
  return __int_as_float(__builtin_amdgcn_ds_swizzle(__float_as_int(v), P));
}

__device__ __forceinline__ h2f pack2(float a, float b) {
  h2f r; r[0] = (f16)a; r[1] = (f16)b; return r;
}

__global__ __launch_bounds__(THREADS, 2)
void lstm_fused(const float* __restrict__ x,
                const float* __restrict__ Wih1, const float* __restrict__ Whh1,
                const float* __restrict__ bih1, const float* __restrict__ bhh1,
                const float* __restrict__ Wih2, const float* __restrict__ Whh2,
                const float* __restrict__ bih2, const float* __restrict__ bhh2,
                const float* __restrict__ fc1w, const float* __restrict__ fc1b,
                const float* __restrict__ fc2w, const float* __restrict__ fc2b,
                float* __restrict__ out)
{
  __shared__ Smem s;
  const int tid = threadIdx.x;
  const int b0  = blockIdx.x * NB;

  // L1 role: 4-way k-pair slice, one unit per lane
  const int ks1 = tid & 3;          // k-pair slice 0..3
  const int u1  = tid >> 2;         // unit 0..63
  // L2 role: 8-way k-pair slice
  const int ks2 = tid & 7;          // k-pair slice 0..7 (also final batch)
  const int u2  = tid >> 3;         // unit 0..31

  h2f w1[12][4];                    // L1: k-pair row r = ks1+4j, gate g
  h2f w2[6][4];                     // L2: k-pair row r = ks2+8j, gate g

  auto stage = [&](const float* g, int n) {
    for (int e = tid * 4; e < n; e += THREADS * 4)
      *(float4*)&s.scr[e] = *(const float4*)&g[e];
  };

  // ---- phase 1: Wih1 [256][32] -> w1[j<4] (k-pairs {2r,2r+1}, r=ks1+4j<16) ----
  stage(Wih1, 8192);
  __syncthreads();
#pragma unroll
  for (int j = 0; j < 4; ++j) {
    int col = 2 * (ks1 + 4 * j);
#pragma unroll
    for (int g = 0; g < 4; ++g)
      w1[j][g] = pack2(s.scr[(g * 64 + u1) * 32 + col],
                       s.scr[(g * 64 + u1) * 32 + col + 1]);
  }
  __syncthreads();

  // ---- phase 2a: Whh1 rows 0..127 (gates 0,1) [.][64] ----
  stage(Whh1, 8192);
  __syncthreads();
#pragma unroll
  for (int j = 4; j < 12; ++j) {
    int col = 2 * (ks1 + 4 * j) - 32;          // 0..62
#pragma unroll
    for (int g = 0; g < 2; ++g)
      w1[j][g] = pack2(s.scr[(g * 64 + u1) * 64 + col],
                       s.scr[(g * 64 + u1) * 64 + col + 1]);
  }
  __syncthreads();

  // ---- phase 2b: Whh1 rows 128..255 (gates 2,3) ----
  stage(Whh1 + 8192, 8192);
  __syncthreads();
#pragma unroll
  for (int j = 4; j < 12; ++j) {
    int col = 2 * (ks1 + 4 * j) - 32;
#pragma unroll
    for (int g = 2; g < 4; ++g)
      w1[j][g] = pack2(s.scr[((g - 2) * 64 + u1) * 64 + col],
                       s.scr[((g - 2) * 64 + u1) * 64 + col + 1]);
  }
  __syncthreads();

  // ---- phase 3: Wih2 [128][64] -> w2[j<4] (r=ks2+8j<32) ----
  stage(Wih2, 8192);
  __syncthreads();
#pragma unroll
  for (int j = 0; j < 4; ++j) {
    int col = 2 * (ks2 + 8 * j);               // 0..62
#pragma unroll
    for (int g = 0; g < 4; ++g)
      w2[j][g] = pack2(s.scr[(g * 32 + u2) * 64 + col],
                       s.scr[(g * 32 + u2) * 64 + col + 1]);
  }
  __syncthreads();

  // ---- phase 4: Whh2 [128][32] -> w2[j>=4] (r=ks2+8j in [32,48)) ----
  stage(Whh2, 4096);
  __syncthreads();
#pragma unroll
  for (int j = 4; j < 6; ++j) {
    int col = 2 * (ks2 + 8 * j) - 64;          // 0..30
#pragma unroll
    for (int g = 0; g < 4; ++g)
      w2[j][g] = pack2(s.scr[(g * 32 + u2) * 32 + col],
                       s.scr[(g * 32 + u2) * 32 + col + 1]);
  }

  // biases (fused)
  float bias1[4], bias2[4];
#pragma unroll
  for (int g = 0; g < 4; ++g) {
    bias1[g] = bih1[g * 64 + u1] + bhh1[g * 64 + u1];
    bias2[g] = bih2[g * 32 + u2] + bhh2[g * 32 + u2];
  }

  // zero initial state (buffer 0)
  if (tid < 256) {
    uint* z1 = (uint*)&s.h1p[0][0][0];         // 256 dwords
    z1[tid] = 0u;
  }
  if (tid < 128) {
    uint* z2 = (uint*)&s.h2p[0][0][0];         // 128 dwords
    z2[tid] = 0u;
  }

  // x staging: tid<128 owns (xb, xr) feature-pair; coalesced float2 global read
  const int    xb   = tid >> 4;                // 0..7
  const int    xr   = tid & 15;                // 0..15
  const float* xptr = x + (size_t)(b0 + xb) * (Tt * 32) + 2 * xr;
  if (tid < 128) {
    float2 x0 = *(const float2*)xptr;
    s.xsp[0][xr][xb] = pack2(x0.x, x0.y);
  }

  float c1[2] = {0.0f, 0.0f};                  // lane's batches: ks1, ks1+4
  float c2    = 0.0f;                          // lane's batch: ks2

  const bool sA = (ks1 & 1) != 0;
  const bool sB = (ks1 & 2) != 0;
  const bool t0 = (ks2 & 1) != 0;
  const bool t1 = (ks2 & 2) != 0;
  const bool t2 = (ks2 & 4) != 0;

  __syncthreads();

#pragma unroll 1
  for (int t = 0; t < Tt; ++t) {
    const int c = t & 1, n = c ^ 1;

    float2 xpre = make_float2(0.0f, 0.0f);
    if (tid < 128 && t + 1 < Tt) xpre = *(const float2*)(xptr + (size_t)(t + 1) * 32);

    // ============ Layer 1: partials over k-pair rows r = ks1 + 4j ============
    float a[4][8];
#pragma unroll
    for (int g = 0; g < 4; ++g)
#pragma unroll
      for (int b = 0; b < 8; ++b) a[g][b] = 0.0f;

#pragma unroll
    for (int j = 0; j < 12; ++j) {
      const h8f* row = (j < 4) ? (const h8f*)&s.xsp[c][ks1 + 4 * j][0]
                               : (const h8f*)&s.h1p[c][ks1 + 4 * j - 16][0];
      union { h8f v; h2f p[4]; } U0, U1;
      U0.v = row[0];                           // batches 0..3
      U1.v = row[1];                           // batches 4..7
#pragma unroll
      for (int g = 0; g < 4; ++g) {
#pragma unroll
        for (int b = 0; b < 4; ++b)
          a[g][b] = __builtin_amdgcn_fdot2(w1[j][g], U0.p[b], a[g][b], false);
#pragma unroll
        for (int b = 0; b < 4; ++b)
          a[g][4 + b] = __builtin_amdgcn_fdot2(w1[j][g], U1.p[b], a[g][4 + b], false);
      }
    }

    // 2-round reduce-scatter across 4 slices -> lane owns batches {ks1, ks1+4}
    float tot[4][2];
#pragma unroll
    for (int g = 0; g < 4; ++g) {
      float r1[4];
#pragma unroll
      for (int i = 0; i < 4; ++i) {
        float snd  = sA ? a[g][2 * i]     : a[g][2 * i + 1];
        float kept = sA ? a[g][2 * i + 1] : a[g][2 * i];
        r1[i] = kept + swz<0x041F>(snd);
      }
#pragma unroll
      for (int i = 0; i < 2; ++i) {
        float snd  = sB ? r1[2 * i]     : r1[2 * i + 1];
        float kept = sB ? r1[2 * i + 1] : r1[2 * i];
        tot[g][i] = kept + swz<0x081F>(snd);
      }
    }

#pragma unroll
    for (int bb = 0; bb < 2; ++bb) {
      float iv = fsig  (tot[0][bb] + bias1[0]);
      float fv = fsig  (tot[1][bb] + bias1[1]);
      float gv = ftanh_(tot[2][bb] + bias1[2]);
      float ov = fsig  (tot[3][bb] + bias1[3]);
      c1[bb] = fv * c1[bb] + iv * gv;
      float hval = ov * ftanh_(c1[bb]);
      // f16 store into half-slot (u1&1) of unit-pair row u1>>1
      f16* dst = (f16*)&s.h1p[n][u1 >> 1][ks1 + 4 * bb];
      dst[u1 & 1] = (f16)hval;
    }
    __syncthreads();   // A: h1(t) complete; xs[c] consumed

    if (tid < 128 && t + 1 < Tt) s.xsp[n][xr][xb] = pack2(xpre.x, xpre.y);

    // ============ Layer 2: partials over k-pair rows r = ks2 + 8j ============
    float a2[4][8];
#pragma unroll
    for (int g = 0; g < 4; ++g)
#pragma unroll
      for (int b = 0; b < 8; ++b) a2[g][b] = 0.0f;

#pragma unroll
    for (int j = 0; j < 6; ++j) {
      const h8f* row = (j < 4) ? (const h8f*)&s.h1p[n][ks2 + 8 * j][0]
                               : (const h8f*)&s.h2p[c][ks2 + 8 * j - 32][0];
      union { h8f v; h2f p[4]; } U0, U1;
      U0.v = row[0];
      U1.v = row[1];
#pragma unroll
      for (int g = 0; g < 4; ++g) {
#pragma unroll
        for (int b = 0; b < 4; ++b)
          a2[g][b] = __builtin_amdgcn_fdot2(w2[j][g], U0.p[b], a2[g][b], false);
#pragma unroll
        for (int b = 0; b < 4; ++b)
          a2[g][4 + b] = __builtin_amdgcn_fdot2(w2[j][g], U1.p[b], a2[g][4 + b], false);
      }
    }

    // 3-round reduce-scatter across 8 slices -> lane owns batch ks2
    float tot2[4];
#pragma unroll
    for (int g = 0; g < 4; ++g) {
      float r1[4];
#pragma unroll
      for (int i = 0; i < 4; ++i) {
        float snd  = t0 ? a2[g][2 * i]     : a2[g][2 * i + 1];
        float kept = t0 ? a2[g][2 * i + 1] : a2[g][2 * i];
        r1[i] = kept + swz<0x041F>(snd);
      }
      float r2[2];
#pragma unroll
      for (int i = 0; i < 2; ++i) {
        float snd  = t1 ? r1[2 * i]     : r1[2 * i + 1];
        float kept = t1 ? r1[2 * i + 1] : r1[2 * i];
        r2[i] = kept + swz<0x081F>(snd);
      }
      float snd  = t2 ? r2[0] : r2[1];
      float kept = t2 ? r2[1] : r2[0];
      tot2[g] = kept + swz<0x101F>(snd);
    }

    {
      float iv = fsig  (tot2[0] + bias2[0]);
      float fv = fsig  (tot2[1] + bias2[1]);
      float gv = ftanh_(tot2[2] + bias2[2]);
      float ov = fsig  (tot2[3] + bias2[3]);
      c2 = fv * c2 + iv * gv;
      float hval = ov * ftanh_(c2);
      f16* dst = (f16*)&s.h2p[n][u2 >> 1][ks2];
      dst[u2 & 1] = (f16)hval;
    }
    __syncthreads();   // B: h2(t), xs[next] visible
  }

  // ---------------- FC head ----------------
  // final h2 in buffer 0 (t=127: n=0); scr is dead -> scratch
  float* fc1out = s.scr;            // [8 batches][16 units]
  if (tid < 128) {
    const int fb = tid >> 4, fu = tid & 15;
    const f16* h2flat = (const f16*)&s.h2p[0][0][0];
    float sacc = fc1b[fu];
#pragma unroll
    for (int k = 0; k < 32; ++k) {
      float hv = (float)h2flat[(k >> 1) * 16 + fb * 2 + (k & 1)];
      sacc = fmaf(fc1w[fu * 32 + k], hv, sacc);
    }
    fc1out[fb * 16 + fu] = fmaxf(sacc, 0.0f);
  }
  __syncthreads();
  if (tid < NB) {
    float o = fc2b[0];
#pragma unroll
    for (int u = 0; u < 16; ++u) o = fmaf(fc2w[u], fc1out[tid * 16 + u], o);
    out[b0 + tid] = o;
  }
}

extern "C" void kernel_launch(void* const* d_in, const int* in_sizes, int n_in,
                              void* d_out, int out_size, void* d_ws, size_t ws_size,
                              hipStream_t stream) {
  const float* x    = (const float*)d_in[0];
  const float* Wih1 = (const float*)d_in[1];
  const float* Whh1 = (const float*)d_in[2];
  const float* bih1 = (const float*)d_in[3];
  const float* bhh1 = (const float*)d_in[4];
  const float* Wih2 = (const float*)d_in[5];
  const float* Whh2 = (const float*)d_in[6];
  const float* bih2 = (const float*)d_in[7];
  const float* bhh2 = (const float*)d_in[8];
  const float* fc1w = (const float*)d_in[9];
  const float* fc1b = (const float*)d_in[10];
  const float* fc2w = (const float*)d_in[11];
  const float* fc2b = (const float*)d_in[12];
  float* out = (float*)d_out;

  hipLaunchKernelGGL(lstm_fused, dim3(4096 / NB), dim3(THREADS), 0, stream,
                     x, Wih1, Whh1, bih1, bhh1,
                     Wih2, Whh2, bih2, bhh2,
                     fc1w, fc1b, fc2w, fc2b, out);
}

// Round 11
// 615.944 us; speedup vs baseline: 1.1060x; 1.0359x over previous
//
#include <hip/hip_runtime.h>

// Fused 2-layer LSTM + FC head: B=4096, T=128, D=32, H1=64, H2=32.
// 256 threads/block, NB=4 batches/block, grid=1024 (4 blocks/CU, 16 waves/CU).
// Gate matmuls via v_dot2_f32_f16 (f32 accumulate), weights register-resident
// as half2 k-pairs. Whole x tile pre-converted to f16 in LDS (reuses the 32KB
// weight-staging scratch) -> no global loads in the recurrent loop.
// ONE barrier per timestep (race audit in loop comments).

typedef _Float16 f16;
typedef f16 h2f __attribute__((ext_vector_type(2)));
typedef f16 h8f __attribute__((ext_vector_type(8)));

constexpr int Tt      = 128;
constexpr int NB      = 4;
constexpr int THREADS = 256;

struct __align__(16) Smem {
  float scr[8192];           // init: weight staging; then x tile as h2f [t][dpair][batch]
  h2f h1p[2][32][4];         // [buf][unit-pair][batch]   1024 B
  h2f h2p[2][16][4];         // [buf][unit-pair][batch]    512 B
  float fcs[64];             // FC scratch                 256 B
};                           // 34560 B -> 4 blocks/CU (138 KB of 160 KB)

static_assert(sizeof(Smem) <= 40 * 1024, "need 4 blocks/CU");

__device__ __forceinline__ float frcp(float x)   { return __builtin_amdgcn_rcpf(x); }
__device__ __forceinline__ float fsig(float x)   { return frcp(1.0f + __expf(-x)); }
__device__ __forceinline__ float ftanh_(float x) { return 1.0f - 2.0f * frcp(1.0f + __expf(2.0f * x)); }

template<int P>
__device__ __forceinline__ float swz(float v) {
  return __int_as_float(__builtin_amdgcn_ds_swizzle(__float_as_int(v), P));
}

__device__ __forceinline__ h2f pack2(float a, float b) {
  h2f r; r[0] = (f16)a; r[1] = (f16)b; return r;
}

__global__ __launch_bounds__(THREADS, 4)
void lstm_fused(const float* __restrict__ x,
                const float* __restrict__ Wih1, const float* __restrict__ Whh1,
                const float* __restrict__ bih1, const float* __restrict__ bhh1,
                const float* __restrict__ Wih2, const float* __restrict__ Whh2,
                const float* __restrict__ bih2, const float* __restrict__ bhh2,
                const float* __restrict__ fc1w, const float* __restrict__ fc1b,
                const float* __restrict__ fc2w, const float* __restrict__ fc2b,
                float* __restrict__ out)
{
  __shared__ Smem s;
  const int tid = threadIdx.x;
  const int b0  = blockIdx.x * NB;

  // L1 role: 4-way k-pair slice, one unit per lane
  const int ks1 = tid & 3;          // k-pair slice 0..3 (also final batch)
  const int u1  = tid >> 2;         // unit 0..63
  // L2 role: 8-way k-pair slice
  const int ks2 = tid & 7;          // k-pair slice 0..7 (final batch = ks2&3)
  const int u2  = tid >> 3;         // unit 0..31

  h2f w1[12][4];                    // L1: k-pair row r = ks1+4j, gate g
  h2f w2[6][4];                     // L2: k-pair row r = ks2+8j, gate g

  auto stage = [&](const float* g, int n) {
    for (int e = tid * 4; e < n; e += THREADS * 4)
      *(float4*)&s.scr[e] = *(const float4*)&g[e];
  };

  // ---- phase 1: Wih1 [256][32] -> w1[j<4] (k-pair rows r=ks1+4j<16) ----
  stage(Wih1, 8192);
  __syncthreads();
#pragma unroll
  for (int j = 0; j < 4; ++j) {
    int col = 2 * (ks1 + 4 * j);
#pragma unroll
    for (int g = 0; g < 4; ++g)
      w1[j][g] = pack2(s.scr[(g * 64 + u1) * 32 + col],
                       s.scr[(g * 64 + u1) * 32 + col + 1]);
  }
  __syncthreads();

  // ---- phase 2a: Whh1 rows 0..127 (gates 0,1) [.][64] ----
  stage(Whh1, 8192);
  __syncthreads();
#pragma unroll
  for (int j = 4; j < 12; ++j) {
    int col = 2 * (ks1 + 4 * j) - 32;          // 0..62
#pragma unroll
    for (int g = 0; g < 2; ++g)
      w1[j][g] = pack2(s.scr[(g * 64 + u1) * 64 + col],
                       s.scr[(g * 64 + u1) * 64 + col + 1]);
  }
  __syncthreads();

  // ---- phase 2b: Whh1 rows 128..255 (gates 2,3) ----
  stage(Whh1 + 8192, 8192);
  __syncthreads();
#pragma unroll
  for (int j = 4; j < 12; ++j) {
    int col = 2 * (ks1 + 4 * j) - 32;
#pragma unroll
    for (int g = 2; g < 4; ++g)
      w1[j][g] = pack2(s.scr[((g - 2) * 64 + u1) * 64 + col],
                       s.scr[((g - 2) * 64 + u1) * 64 + col + 1]);
  }
  __syncthreads();

  // ---- phase 3: Wih2 [128][64] -> w2[j<4] (r=ks2+8j<32) ----
  stage(Wih2, 8192);
  __syncthreads();
#pragma unroll
  for (int j = 0; j < 4; ++j) {
    int col = 2 * (ks2 + 8 * j);               // 0..62
#pragma unroll
    for (int g = 0; g < 4; ++g)
      w2[j][g] = pack2(s.scr[(g * 32 + u2) * 64 + col],
                       s.scr[(g * 32 + u2) * 64 + col + 1]);
  }
  __syncthreads();

  // ---- phase 4: Whh2 [128][32] -> w2[4..5] (r=ks2+8j in [32,48)) ----
  stage(Whh2, 4096);
  __syncthreads();
#pragma unroll
  for (int j = 4; j < 6; ++j) {
    int col = 2 * (ks2 + 8 * j) - 64;          // 0..30
#pragma unroll
    for (int g = 0; g < 4; ++g)
      w2[j][g] = pack2(s.scr[(g * 32 + u2) * 32 + col],
                       s.scr[(g * 32 + u2) * 32 + col + 1]);
  }
  __syncthreads();   // all weight reads from scr done -> scr reusable for x

  // ---- phase 5: whole x tile -> f16 in scr: xf[t][dpair(16)][batch(4)] ----
  {
    h2f* xf = (h2f*)s.scr;                     // 128*16*4 = 8192 h2f = 32 KB
    const int dp = tid & 15;                   // feature pair
    const int t0 = (tid >> 4) & 3;             // t offset
    const int xb = tid >> 6;                   // batch 0..3
    const float* xp = x + (size_t)(b0 + xb) * (Tt * 32) + 2 * dp;
#pragma unroll 4
    for (int i = 0; i < 32; ++i) {
      int t = t0 + 4 * i;
      float2 v = *(const float2*)(xp + (size_t)t * 32);
      xf[t * 64 + dp * 4 + xb] = pack2(v.x, v.y);
    }
  }

  // biases (fused)
  float bias1[4], bias2[4];
#pragma unroll
  for (int g = 0; g < 4; ++g) {
    bias1[g] = bih1[g * 64 + u1] + bhh1[g * 64 + u1];
    bias2[g] = bih2[g * 32 + u2] + bhh2[g * 32 + u2];
  }

  // zero initial state (buffer 0)
  if (tid < 128) ((uint*)&s.h1p[0][0][0])[tid] = 0u;
  if (tid < 64)  ((uint*)&s.h2p[0][0][0])[tid] = 0u;

  float c1 = 0.0f;                  // lane's (unit u1, batch ks1) cell
  float c2 = 0.0f;                  // lane's (unit u2, batch ks2&3) cell (dup over ks2&4)

  const bool sA = (ks1 & 1) != 0;
  const bool sB = (ks1 & 2) != 0;
  const bool t0b = (ks2 & 1) != 0;
  const bool t1b = (ks2 & 2) != 0;

  const h2f* xf = (const h2f*)s.scr;

  __syncthreads();

  // Race audit (single barrier A per step):
  //  h1p[n]: written pre-A(t), read (L1-dots t+1, L2-dots t) post-A(t). OK.
  //  h2p[n]: written post-A(t); read at L2-dots(t+1) which is post-A(t+1);
  //          all waves pass L2-finalize(t) before reaching A(t+1). OK.
  //  buffer reuse h1p[c]: last read pre-A(t) (L1-dots t), rewritten post-A(t)
  //          at L1-finalize(t+1). OK.  h2p[c]: last read L2-dots(t) pre-A(t+1),
  //          rewritten L2-finalize(t+1) post-A(t+1). OK.  xf is read-only.
#pragma unroll 1
  for (int t = 0; t < Tt; ++t) {
    const int c = t & 1, n = c ^ 1;

    // ============ Layer 1: partials over k-pair rows r = ks1 + 4j ============
    float a[4][4];
#pragma unroll
    for (int g = 0; g < 4; ++g)
#pragma unroll
      for (int b = 0; b < 4; ++b) a[g][b] = 0.0f;

#pragma unroll
    for (int j = 0; j < 12; ++j) {
      const h8f row = (j < 4) ? *(const h8f*)&xf[t * 64 + (ks1 + 4 * j) * 4]
                              : *(const h8f*)&s.h1p[c][ks1 + 4 * j - 16][0];
      union { h8f v; h2f p[4]; } U; U.v = row;
#pragma unroll
      for (int g = 0; g < 4; ++g)
#pragma unroll
        for (int b = 0; b < 4; ++b)
          a[g][b] = __builtin_amdgcn_fdot2(w1[j][g], U.p[b], a[g][b], false);
    }

    // 2-round reduce-scatter over 4 slices -> lane owns batch ks1
    float tot[4];
#pragma unroll
    for (int g = 0; g < 4; ++g) {
      float r1[2];
#pragma unroll
      for (int i = 0; i < 2; ++i) {
        float snd  = sA ? a[g][2 * i]     : a[g][2 * i + 1];
        float kept = sA ? a[g][2 * i + 1] : a[g][2 * i];
        r1[i] = kept + swz<0x041F>(snd);
      }
      float snd  = sB ? r1[0] : r1[1];
      float kept = sB ? r1[1] : r1[0];
      tot[g] = kept + swz<0x081F>(snd);
    }

    {
      float iv = fsig  (tot[0] + bias1[0]);
      float fv = fsig  (tot[1] + bias1[1]);
      float gv = ftanh_(tot[2] + bias1[2]);
      float ov = fsig  (tot[3] + bias1[3]);
      c1 = fv * c1 + iv * gv;
      float hval = ov * ftanh_(c1);
      ((f16*)&s.h1p[n][u1 >> 1][ks1])[u1 & 1] = (f16)hval;
    }
    __syncthreads();   // A: h1(t) complete

    // ============ Layer 2: partials over k-pair rows r = ks2 + 8j ============
    float a2[4][4];
#pragma unroll
    for (int g = 0; g < 4; ++g)
#pragma unroll
      for (int b = 0; b < 4; ++b) a2[g][b] = 0.0f;

#pragma unroll
    for (int j = 0; j < 6; ++j) {
      const h8f row = (j < 4) ? *(const h8f*)&s.h1p[n][ks2 + 8 * j][0]
                              : *(const h8f*)&s.h2p[c][ks2 + 8 * j - 32][0];
      union { h8f v; h2f p[4]; } U; U.v = row;
#pragma unroll
      for (int g = 0; g < 4; ++g)
#pragma unroll
        for (int b = 0; b < 4; ++b)
          a2[g][b] = __builtin_amdgcn_fdot2(w2[j][g], U.p[b], a2[g][b], false);
    }

    // reduce over 8 slices, 4 items: 2 select rounds + 1 plain add.
    // lane ends with batch ks2&3 (duplicated across ks2&4).
    float tot2[4];
#pragma unroll
    for (int g = 0; g < 4; ++g) {
      float r1[2];
#pragma unroll
      for (int i = 0; i < 2; ++i) {
        float snd  = t0b ? a2[g][2 * i]     : a2[g][2 * i + 1];
        float kept = t0b ? a2[g][2 * i + 1] : a2[g][2 * i];
        r1[i] = kept + swz<0x041F>(snd);
      }
      float snd  = t1b ? r1[0] : r1[1];
      float kept = t1b ? r1[1] : r1[0];
      float r2 = kept + swz<0x081F>(snd);
      tot2[g] = r2 + swz<0x101F>(r2);
    }

    {
      float iv = fsig  (tot2[0] + bias2[0]);
      float fv = fsig  (tot2[1] + bias2[1]);
      float gv = ftanh_(tot2[2] + bias2[2]);
      float ov = fsig  (tot2[3] + bias2[3]);
      c2 = fv * c2 + iv * gv;
      float hval = ov * ftanh_(c2);
      if (ks2 < 4)
        ((f16*)&s.h2p[n][u2 >> 1][ks2 & 3])[u2 & 1] = (f16)hval;
    }
    // no barrier here: next step's A protects h2p[n] before its first read.
  }
  __syncthreads();     // final h2 (buffer 0) visible

  // ---------------- FC head ----------------
  if (tid < 64) {
    const int fb = tid >> 4, fu = tid & 15;
    float sacc = fc1b[fu];
#pragma unroll
    for (int k = 0; k < 32; ++k) {
      float hv = (float)(((const f16*)&s.h2p[0][k >> 1][fb])[k & 1]);
      sacc = fmaf(fc1w[fu * 32 + k], hv, sacc);
    }
    s.fcs[fb * 16 + fu] = fmaxf(sacc, 0.0f);
  }
  __syncthreads();
  if (tid < NB) {
    float o = fc2b[0];
#pragma unroll
    for (int u = 0; u < 16; ++u) o = fmaf(fc2w[u], s.fcs[tid * 16 + u], o);
    out[b0 + tid] = o;
  }
}

extern "C" void kernel_launch(void* const* d_in, const int* in_sizes, int n_in,
                              void* d_out, int out_size, void* d_ws, size_t ws_size,
                              hipStream_t stream) {
  const float* x    = (const float*)d_in[0];
  const float* Wih1 = (const float*)d_in[1];
  const float* Whh1 = (const float*)d_in[2];
  const float* bih1 = (const float*)d_in[3];
  const float* bhh1 = (const float*)d_in[4];
  const float* Wih2 = (const float*)d_in[5];
  const float* Whh2 = (const float*)d_in[6];
  const float* bih2 = (const float*)d_in[7];
  const float* bhh2 = (const float*)d_in[8];
  const float* fc1w = (const float*)d_in[9];
  const float* fc1b = (const float*)d_in[10];
  const float* fc2w = (const float*)d_in[11];
  const float* fc2b = (const float*)d_in[12];
  float* out = (float*)d_out;

  hipLaunchKernelGGL(lstm_fused, dim3(4096 / NB), dim3(THREADS), 0, stream,
                     x, Wih1, Whh1, bih1, bhh1,
                     Wih2, Whh2, bih2, bhh2,
                     fc1w, fc1b, fc2w, fc2b, out);
}